// Round 2
// baseline (337.663 us; speedup 1.0000x reference)
//
#include <hip/hip_runtime.h>

// TriDiagonalLaplaceSolver: B=4096 independent rows, N=8192 per row.
// Thomas algorithm with precomputed LU factors a (N), b (N-1), c (N-1).
//   fwd: y[i] = x[i] - c[i-1]*y[i-1]        (y[0] = x[0])
//   bwd: z[i] = (y[i] - b[i]*z[i+1])/a[i]   (z[N-1] = y[N-1]/a[N-1])
// Both recurrences contract with ratio ~0.268/step => HALO=32 zero-init
// warm-up reproduces exact state to ~5e-19 relative error.
//
// R1 lesson: WIN=160 ybuf spilled (VGPR_Count=128, +156 MB spill writes).
// R2: CHUNK=64, WIN=96 -> ~115 live VGPRs, fits under the 128-VGPR cap of
// __launch_bounds__(256,4) (4 waves/SIMD, 50% occupancy). z computed in
// place into ybuf, stored ascending back-to-back so output lines are fully
// dirtied quickly (minimize partial-line eviction).

#define NN    8192
#define BB    4096
#define CHUNK 64
#define HALO  32
#define WIN   (CHUNK + HALO)   // register y-window per thread

__device__ __forceinline__ float fast_rcp(float v) {
    float r = __builtin_amdgcn_rcpf(v);
    r = r * (2.0f - v * r);   // one NR step -> ~0.5 ulp
    return r;
}

template<bool FIRST, bool EDGE>
__device__ __forceinline__ void solve_window(
    const float* __restrict__ xrow,
    const float* __restrict__ a,
    const float* __restrict__ b,
    const float* __restrict__ c,
    float* __restrict__ orow,
    int s)
{
    const float* xs = xrow + s;
    const float* as = a + s;
    const float* bs = b + s;
    const float* cs = c + s;   // c[i-1] == cs[k-1]

    float y = 0.0f;

    if (!FIRST) {
        // forward warm-up over [s-HALO, s): contraction kills the zero-init err
        const float* xw = xrow + (s - HALO);
        const float* cw = c + (s - HALO);
        #pragma unroll
        for (int k = 0; k < HALO; k += 4) {
            float4 xv = *(const float4*)(xw + k);
            y = xv.x - cw[k - 1] * y;
            y = xv.y - cw[k]     * y;
            y = xv.z - cw[k + 1] * y;
            y = xv.w - cw[k + 2] * y;
        }
    }

    // forward main: y over [s, s+WIN)  (EDGE: only [s, s+CHUNK), ends at N)
    float ybuf[WIN];
    #pragma unroll
    for (int k = 0; k < (EDGE ? CHUNK : WIN); k += 4) {
        float4 xv = *(const float4*)(xs + k);
        float c0 = (FIRST && k == 0) ? 0.0f : cs[k - 1];
        y = xv.x - c0        * y;  ybuf[k]     = y;
        y = xv.y - cs[k]     * y;  ybuf[k + 1] = y;
        y = xv.z - cs[k + 1] * y;  ybuf[k + 2] = y;
        y = xv.w - cs[k + 2] * y;  ybuf[k + 3] = y;
    }

    // backward: z computed in place into ybuf (register reuse)
    float z = 0.0f;
    if (!EDGE) {
        // warm-up over [s+CHUNK, s+WIN): z state converges, values discarded
        #pragma unroll
        for (int k = WIN - 1; k >= CHUNK; --k) {
            z = (ybuf[k] - bs[k] * z) * fast_rcp(as[k]);
        }
        #pragma unroll
        for (int k = CHUNK - 1; k >= 0; --k) {
            z = (ybuf[k] - bs[k] * z) * fast_rcp(as[k]);
            ybuf[k] = z;
        }
    } else {
        // last chunk: z[N-1] = y[N-1]/a[N-1]  (b_pad[N-1]=0, z starts at 0)
        z = ybuf[CHUNK - 1] * fast_rcp(as[CHUNK - 1]);
        ybuf[CHUNK - 1] = z;
        #pragma unroll
        for (int k = CHUNK - 2; k >= 0; --k) {
            z = (ybuf[k] - bs[k] * z) * fast_rcp(as[k]);
            ybuf[k] = z;
        }
    }

    // store ascending, back-to-back: full 128B lines dirtied within a few
    // instructions -> L2 write-combines to full-line HBM writes
    #pragma unroll
    for (int k = 0; k < CHUNK; k += 4) {
        float4 zv;
        zv.x = ybuf[k];
        zv.y = ybuf[k + 1];
        zv.z = ybuf[k + 2];
        zv.w = ybuf[k + 3];
        *(float4*)(orow + s + k) = zv;
    }
}

__global__ __launch_bounds__(256, 4) void TriDiagonalLaplaceSolver_kernel(
    const float* __restrict__ x,
    const float* __restrict__ a,
    const float* __restrict__ b,
    const float* __restrict__ c,
    float* __restrict__ out)
{
    const int chunk = blockIdx.x;                    // 0 .. NN/CHUNK-1
    const int row   = blockIdx.y * 256 + threadIdx.x;
    const int s     = chunk * CHUNK;

    const float* xrow = x   + (size_t)row * NN;
    float*       orow = out + (size_t)row * NN;

    if (chunk == 0) {
        solve_window<true, false>(xrow, a, b, c, orow, 0);
    } else if (chunk == (NN / CHUNK) - 1) {
        solve_window<false, true>(xrow, a, b, c, orow, s);
    } else {
        solve_window<false, false>(xrow, a, b, c, orow, s);
    }
}

extern "C" void kernel_launch(void* const* d_in, const int* in_sizes, int n_in,
                              void* d_out, int out_size, void* d_ws, size_t ws_size,
                              hipStream_t stream) {
    const float* x = (const float*)d_in[0];
    const float* a = (const float*)d_in[1];
    const float* b = (const float*)d_in[2];
    const float* c = (const float*)d_in[3];
    float* out = (float*)d_out;

    dim3 grid(NN / CHUNK, BB / 256);   // 128 chunks x 16 row-groups = 2048 blocks
    dim3 block(256);
    TriDiagonalLaplaceSolver_kernel<<<grid, block, 0, stream>>>(x, a, b, c, out);
}

// Round 3
// 308.210 us; speedup vs baseline: 1.0956x; 1.0956x over previous
//
#include <hip/hip_runtime.h>

// TriDiagonalLaplaceSolver: B=4096 independent rows, N=8192 per row.
// Thomas algorithm with precomputed LU factors a (N), b (N-1), c (N-1).
//   fwd: y[i] = x[i] - c[i-1]*y[i-1]        (y[0] = x[0])
//   bwd: z[i] = (y[i] - b[i]*z[i+1])/a[i]   (z[N-1] = y[N-1]/a[N-1])
// Both recurrences contract with ratio ~0.268/step => HALO=16 zero-init
// warm-up reproduces exact state to ~7e-10 relative (fp32 noise is 1e-7).
//
// R1/R2 lesson: a float ybuf[WIN] ARRAY is an alloca; AMDGPUPromoteAlloca's
// occupancy heuristic refused to promote it (R2: VGPR_Count=64, whole window
// went through scratch: +178 MB writes, +100 MB reads). Fix: ybuf is an
// ext_vector_type value -> SSA, register-allocated per element, no alloca.
// All ybuf subscripts are constants after full unroll (template-const bounds).

#define NN    8192
#define BB    4096
#define CHUNK 64
#define HALO  16
#define WIN   (CHUNK + HALO)   // 80 floats live in VGPRs per thread

typedef float yvec_t __attribute__((ext_vector_type(WIN)));

__device__ __forceinline__ float fast_rcp(float v) {
    float r = __builtin_amdgcn_rcpf(v);
    return r * (2.0f - v * r);   // one NR step -> ~0.5 ulp
}

template<bool FIRST, bool EDGE>
__device__ __forceinline__ void solve_window(
    const float* __restrict__ xrow,
    const float* __restrict__ a,
    const float* __restrict__ b,
    const float* __restrict__ c,
    float* __restrict__ orow,
    int s)
{
    const float* xs = xrow + s;
    const float* as = a + s;
    const float* bs = b + s;
    const float* cs = c + s;   // c[i-1] == cs[k-1]

    float y = 0.0f;

    if (!FIRST) {
        // forward warm-up over [s-HALO, s): contraction kills zero-init error
        const float* xw = xrow + (s - HALO);
        const float* cw = c + (s - HALO);
        #pragma unroll
        for (int k = 0; k < HALO; k += 4) {
            float4 xv = *(const float4*)(xw + k);
            y = xv.x - cw[k - 1] * y;
            y = xv.y - cw[k]     * y;
            y = xv.z - cw[k + 1] * y;
            y = xv.w - cw[k + 2] * y;
        }
    }

    // forward main: y over [s, s+WIN)  (EDGE: only [s, s+CHUNK), ends at N)
    yvec_t ybuf;
    #pragma unroll
    for (int k = 0; k < (EDGE ? CHUNK : WIN); k += 4) {
        float4 xv = *(const float4*)(xs + k);
        float c0 = (FIRST && k == 0) ? 0.0f : cs[k - 1];
        y = xv.x - c0        * y;  ybuf[k]     = y;
        y = xv.y - cs[k]     * y;  ybuf[k + 1] = y;
        y = xv.z - cs[k + 1] * y;  ybuf[k + 2] = y;
        y = xv.w - cs[k + 2] * y;  ybuf[k + 3] = y;
    }

    // backward: z computed in place into ybuf (register reuse)
    float z = 0.0f;
    if (!EDGE) {
        // z warm-up over [s+CHUNK, s+WIN): state converges, values discarded
        #pragma unroll
        for (int k = WIN - 1; k >= CHUNK; --k) {
            z = (ybuf[k] - bs[k] * z) * fast_rcp(as[k]);
        }
        #pragma unroll
        for (int k = CHUNK - 1; k >= 0; --k) {
            z = (ybuf[k] - bs[k] * z) * fast_rcp(as[k]);
            ybuf[k] = z;
        }
    } else {
        // last chunk: z[N-1] = y[N-1]/a[N-1]  (b_pad[N-1]=0, z starts at 0)
        z = ybuf[CHUNK - 1] * fast_rcp(as[CHUNK - 1]);
        ybuf[CHUNK - 1] = z;
        #pragma unroll
        for (int k = CHUNK - 2; k >= 0; --k) {
            z = (ybuf[k] - bs[k] * z) * fast_rcp(as[k]);
            ybuf[k] = z;
        }
    }

    // store ascending, back-to-back float4s
    #pragma unroll
    for (int k = 0; k < CHUNK; k += 4) {
        float4 zv;
        zv.x = ybuf[k];
        zv.y = ybuf[k + 1];
        zv.z = ybuf[k + 2];
        zv.w = ybuf[k + 3];
        *(float4*)(orow + s + k) = zv;
    }
}

__global__ __launch_bounds__(256, 4) void TriDiagonalLaplaceSolver_kernel(
    const float* __restrict__ x,
    const float* __restrict__ a,
    const float* __restrict__ b,
    const float* __restrict__ c,
    float* __restrict__ out)
{
    const int chunk = blockIdx.x;                    // 0 .. NN/CHUNK-1
    const int row   = blockIdx.y * 256 + threadIdx.x;
    const int s     = chunk * CHUNK;

    const float* xrow = x   + (size_t)row * NN;
    float*       orow = out + (size_t)row * NN;

    if (chunk == 0) {
        solve_window<true, false>(xrow, a, b, c, orow, 0);
    } else if (chunk == (NN / CHUNK) - 1) {
        solve_window<false, true>(xrow, a, b, c, orow, s);
    } else {
        solve_window<false, false>(xrow, a, b, c, orow, s);
    }
}

extern "C" void kernel_launch(void* const* d_in, const int* in_sizes, int n_in,
                              void* d_out, int out_size, void* d_ws, size_t ws_size,
                              hipStream_t stream) {
    const float* x = (const float*)d_in[0];
    const float* a = (const float*)d_in[1];
    const float* b = (const float*)d_in[2];
    const float* c = (const float*)d_in[3];
    float* out = (float*)d_out;

    dim3 grid(NN / CHUNK, BB / 256);   // 128 chunks x 16 row-groups = 2048 blocks
    dim3 block(256);
    TriDiagonalLaplaceSolver_kernel<<<grid, block, 0, stream>>>(x, a, b, c, out);
}